// Round 2
// baseline (1873.832 us; speedup 1.0000x reference)
//
#include <hip/hip_runtime.h>
#include <stdint.h>

// CustomLoss: out[b] = MAE(all) + [mean(min_n d) + mean(min_b d)] + EMD1d(b)
// pred/target [32,1024,128] fp32 -> out 32 fp32.
//
// ws layout (total 72,351,744 B == round-1 proven size):
//   colmin  u32[32768]    @ 0
//   pnorm   f32[32768]    @ 131072
//   tnorm   f32[32768]    @ 262144
//   emd     f32[32]       @ 393216
//   maeP    f32[8192]     @ 393344
//   minbP   f32[256]      @ 426112
//   minb    u32[1M]       @ 1048576 (4MB; DEAD after k_redminb, then aliased:)
//     spl   u32[64*2047]  @ 1048576
//     base  u32[64*2052]  @ 1572864
//     cnt   u32[64*2052]  @ 2098176
//   keysA   u32[64*131072]@ 5242880
//   keysB   u32[64*131072]@ 38797312

#define B_ 32
#define N_ 1024
#define D_ 128
#define SORTN_ (N_ * D_)
#define JOBS_ 64
#define NB_ 2048
#define NSPL_ 2047
#define BSTRIDE_ 2052

#define OFF_COLMIN 0
#define OFF_PNORM  131072
#define OFF_TNORM  262144
#define OFF_EMD    393216
#define OFF_MAEP   393344
#define OFF_MINBP  426112
#define OFF_MINB   1048576
#define OFF_SPL    1048576
#define OFF_BASE   1572864
#define OFF_CNT    2098176
#define OFF_KEYSA  5242880
#define OFF_KEYSB  38797312

__device__ __forceinline__ unsigned f2k(float f) {
    unsigned u = __float_as_uint(f);
    return (u & 0x80000000u) ? ~u : (u | 0x80000000u);
}
__device__ __forceinline__ float k2f(unsigned k) {
    unsigned u = (k & 0x80000000u) ? (k & 0x7FFFFFFFu) : ~k;
    return __uint_as_float(u);
}

// ---------------- init: +inf the min buffers ----------------
__global__ __launch_bounds__(256) void k_init(unsigned* colmin, unsigned* minb) {
    int i = blockIdx.x * 256 + threadIdx.x;
    int stride = gridDim.x * 256;
    for (int j = i; j < B_ * N_; j += stride) colmin[j] = 0x7F800000u;
    for (int j = i; j < N_ * N_; j += stride) minb[j] = 0x7F800000u;
}

// ---------------- prep: MAE partials, row norms, sort keys ----------------
__global__ __launch_bounds__(256) void k_prep(const float* __restrict__ pred,
                                              const float* __restrict__ tgt,
                                              float* __restrict__ pnorm,
                                              float* __restrict__ tnorm,
                                              unsigned* __restrict__ keys,
                                              float* __restrict__ maeP) {
    __shared__ float red[4];
    int w = threadIdx.x >> 6, lane = threadIdx.x & 63;
    int row = blockIdx.x * 4 + w;
    const float2* p2 = (const float2*)(pred + (size_t)row * D_);
    const float2* t2 = (const float2*)(tgt + (size_t)row * D_);
    float2 p = p2[lane];
    float2 t = t2[lane];
    float mae = fabsf(p.x - t.x) + fabsf(p.y - t.y);
    float pn = p.x * p.x + p.y * p.y;
    float tn = t.x * t.x + t.y * t.y;
    int b = row >> 10, r1 = row & 1023;
    unsigned* kp = keys + (size_t)b * SORTN_ + r1 * D_ + lane * 2;
    kp[0] = f2k(p.x); kp[1] = f2k(p.y);
    unsigned* kt = keys + (size_t)(B_ + b) * SORTN_ + r1 * D_ + lane * 2;
    kt[0] = f2k(t.x); kt[1] = f2k(t.y);
    #pragma unroll
    for (int off = 32; off > 0; off >>= 1) {
        mae += __shfl_down(mae, off);
        pn  += __shfl_down(pn, off);
        tn  += __shfl_down(tn, off);
    }
    if (lane == 0) { pnorm[row] = pn; tnorm[row] = tn; red[w] = mae; }
    __syncthreads();
    if (threadIdx.x == 0) maeP[blockIdx.x] = red[0] + red[1] + red[2] + red[3];
}

// ---------------- chamfer: lane-per-column outer product ----------------
// grid (16 m,16 n,4 bg), block 256 (4 waves). lane = m-col; wave owns 16 n-rows.
// X rows via wave-uniform scalar loads; Y chunk (32 k) staged in LDS, held in 32 VGPRs.
__global__ __launch_bounds__(256) void k_chamfer(const float* __restrict__ pred,
                                                 const float* __restrict__ tgt,
                                                 const float* __restrict__ pnorm,
                                                 const float* __restrict__ tnorm,
                                                 unsigned* __restrict__ colmin,
                                                 unsigned* __restrict__ minb) {
    __shared__ float Ys[64][36];
    __shared__ float colred[4][64];
    int tid = threadIdx.x;
    int lane = tid & 63;
    int wu = __builtin_amdgcn_readfirstlane(tid >> 6);   // wave id as SGPR -> scalar loads
    int m0 = blockIdx.x * 64, n0 = blockIdx.y * 64, bg = blockIdx.z;
    float mreg[16];
    #pragma unroll
    for (int r = 0; r < 16; r++) mreg[r] = 3.0e38f;

    for (int bi = 0; bi < 8; ++bi) {
        int b = bg * 8 + bi;
        float acc0[16], acc1[16];
        #pragma unroll
        for (int r = 0; r < 16; r++) { acc0[r] = 0.f; acc1[r] = 0.f; }
        const float* xw = pred + ((size_t)b * N_ + n0 + wu * 16) * D_;
        for (int kc0 = 0; kc0 < 128; kc0 += 32) {
            __syncthreads();   // protect Ys reuse
            #pragma unroll
            for (int q = 0; q < 2; q++) {
                int lin = q * 256 + tid;          // 0..511 float4s
                int row = lin >> 3, kq = lin & 7;
                *(float4*)&Ys[row][kq * 4] =
                    *(const float4*)&tgt[((size_t)b * N_ + m0 + row) * D_ + kc0 + kq * 4];
            }
            __syncthreads();
            float yv[32];
            #pragma unroll
            for (int q = 0; q < 8; q++)
                *(float4*)&yv[q * 4] = *(float4*)&Ys[lane][q * 4];
            #pragma unroll
            for (int r = 0; r < 16; r++) {
                const float* xr = xw + r * D_ + kc0;   // wave-uniform -> s_load
                #pragma unroll
                for (int k = 0; k < 16; k++) {
                    acc0[r] = fmaf(xr[2 * k],     yv[2 * k],     acc0[r]);
                    acc1[r] = fmaf(xr[2 * k + 1], yv[2 * k + 1], acc1[r]);
                }
            }
        }
        float tnv = tnorm[(size_t)b * N_ + m0 + lane];
        float cmin = 3.0e38f;
        #pragma unroll
        for (int r = 0; r < 16; r++) {
            float pn = pnorm[(size_t)b * N_ + n0 + wu * 16 + r];
            float sq = pn + tnv - 2.0f * (acc0[r] + acc1[r]);
            float d = sqrtf(fmaxf(sq, 1e-12f));
            mreg[r] = fminf(mreg[r], d);
            cmin = fminf(cmin, d);
        }
        colred[wu][lane] = cmin;
        __syncthreads();
        if (tid < 64) {
            float v = fminf(fminf(colred[0][tid], colred[1][tid]),
                            fminf(colred[2][tid], colred[3][tid]));
            atomicMin(&colmin[(size_t)b * N_ + m0 + tid], __float_as_uint(v));
        }
    }
    #pragma unroll
    for (int r = 0; r < 16; r++)
        atomicMin(&minb[(size_t)(n0 + wu * 16 + r) * N_ + m0 + lane],
                  __float_as_uint(mreg[r]));
}

// ---------------- reduce minb -> per-block partials ----------------
__global__ __launch_bounds__(256) void k_redminb(const unsigned* __restrict__ minb,
                                                 float* __restrict__ minbP) {
    __shared__ float red[4];
    float s = 0.f;
    for (int i = blockIdx.x * 256 + threadIdx.x; i < N_ * N_; i += 256 * 256)
        s += __uint_as_float(minb[i]);
    #pragma unroll
    for (int off = 32; off > 0; off >>= 1) s += __shfl_down(s, off);
    int w = threadIdx.x >> 6, lane = threadIdx.x & 63;
    if (lane == 0) red[w] = s;
    __syncthreads();
    if (threadIdx.x == 0) minbP[blockIdx.x] = red[0] + red[1] + red[2] + red[3];
}

// ---------------- samplesort: splitters from data ----------------
__global__ __launch_bounds__(256) void k_splitters(const unsigned* __restrict__ keysA,
                                                   unsigned* __restrict__ spl) {
    __shared__ unsigned s[2048];
    int j = blockIdx.x, tid = threadIdx.x;
    const unsigned* kj = keysA + (size_t)j * SORTN_;
    #pragma unroll
    for (int q = 0; q < 8; q++) s[q * 256 + tid] = kj[(size_t)(q * 256 + tid) * 64];
    __syncthreads();
    for (int k = 2; k <= 2048; k <<= 1)
        for (int jj = k >> 1; jj > 0; jj >>= 1) {
            for (int e = tid; e < 2048; e += 256) {
                int p = e ^ jj;
                if (p > e) {
                    unsigned a = s[e], b2 = s[p];
                    bool up = ((e & k) == 0);
                    if ((a > b2) == up) { s[e] = b2; s[p] = a; }
                }
            }
            __syncthreads();
        }
    for (int t = tid; t < NSPL_; t += 256) spl[(size_t)j * NSPL_ + t] = s[t + 1];
}

__global__ __launch_bounds__(256) void k_zerobase(unsigned* __restrict__ base) {
    int total = JOBS_ * BSTRIDE_;
    for (int t = blockIdx.x * 256 + threadIdx.x; t < total; t += gridDim.x * 256)
        base[t] = 0u;
}

__global__ __launch_bounds__(256) void k_hist(const unsigned* __restrict__ keysA,
                                              const unsigned* __restrict__ spl,
                                              unsigned* __restrict__ base) {
    __shared__ unsigned ls[NSPL_];
    __shared__ unsigned hist[NB_];
    int cx = blockIdx.x, j = blockIdx.y, tid = threadIdx.x;
    for (int t = tid; t < NSPL_; t += 256) ls[t] = spl[(size_t)j * NSPL_ + t];
    for (int t = tid; t < NB_; t += 256) hist[t] = 0u;
    __syncthreads();
    const unsigned* kj = keysA + (size_t)j * SORTN_ + cx * 8192;
    for (int i = 0; i < 32; i++) {
        unsigned key = kj[i * 256 + tid];
        int lo = 0, hi = NSPL_;
        while (lo < hi) { int mid = (lo + hi) >> 1; if (ls[mid] <= key) lo = mid + 1; else hi = mid; }
        atomicAdd(&hist[lo], 1u);
    }
    __syncthreads();
    for (int t = tid; t < NB_; t += 256) {
        unsigned v = hist[t];
        if (v) atomicAdd(&base[j * BSTRIDE_ + t], v);
    }
}

__global__ __launch_bounds__(256) void k_scan(unsigned* __restrict__ base,
                                              unsigned* __restrict__ cnt) {
    __shared__ unsigned partial[256];
    int j = blockIdx.x, tid = threadIdx.x;
    unsigned* bj = base + j * BSTRIDE_;
    unsigned* cj = cnt + j * BSTRIDE_;
    unsigned v[8];
    unsigned s = 0;
    #pragma unroll
    for (int q = 0; q < 8; q++) { v[q] = bj[tid * 8 + q]; s += v[q]; }
    partial[tid] = s;
    __syncthreads();
    for (int off = 1; off < 256; off <<= 1) {
        unsigned add = (tid >= off) ? partial[tid - off] : 0u;
        __syncthreads();
        partial[tid] += add;
        __syncthreads();
    }
    unsigned run = (tid == 0) ? 0u : partial[tid - 1];
    #pragma unroll
    for (int q = 0; q < 8; q++) { unsigned c = v[q]; bj[tid * 8 + q] = run; cj[tid * 8 + q] = run; run += c; }
    if (tid == 255) bj[2048] = run;   // sentinel = 131072
}

__global__ __launch_bounds__(256) void k_scatter(const unsigned* __restrict__ keysA,
                                                 const unsigned* __restrict__ spl,
                                                 unsigned* __restrict__ cnt,
                                                 unsigned* __restrict__ keysB) {
    __shared__ unsigned ls[NSPL_];
    int cx = blockIdx.x, j = blockIdx.y, tid = threadIdx.x;
    for (int t = tid; t < NSPL_; t += 256) ls[t] = spl[(size_t)j * NSPL_ + t];
    __syncthreads();
    const unsigned* kj = keysA + (size_t)j * SORTN_ + cx * 8192;
    unsigned* outj = keysB + (size_t)j * SORTN_;
    for (int i = 0; i < 32; i++) {
        unsigned key = kj[i * 256 + tid];
        int lo = 0, hi = NSPL_;
        while (lo < hi) { int mid = (lo + hi) >> 1; if (ls[mid] <= key) lo = mid + 1; else hi = mid; }
        unsigned pos = atomicAdd(&cnt[j * BSTRIDE_ + lo], 1u);
        outj[pos] = key;
    }
}

// one wave per block; each block sorts 32 consecutive buckets in LDS
__global__ __launch_bounds__(64) void k_bsort(const unsigned* __restrict__ base,
                                              const unsigned* __restrict__ keysB,
                                              unsigned* __restrict__ keysA) {
    __shared__ unsigned lb[2048];
    int j = blockIdx.x, grp = blockIdx.y, lane = threadIdx.x;
    const unsigned* inj = keysB + (size_t)j * SORTN_;
    unsigned* outj = keysA + (size_t)j * SORTN_;
    for (int kb = 0; kb < 32; kb++) {
        int bucket = grp * 32 + kb;
        unsigned lo = base[j * BSTRIDE_ + bucket];
        unsigned hi = base[j * BSTRIDE_ + bucket + 1];
        int count = (int)(hi - lo);
        if (count <= 0) continue;
        if (count == 1) { if (lane == 0) outj[lo] = inj[lo]; continue; }
        int P = 64; while (P < count && P < 2048) P <<= 1;
        __syncthreads();
        for (int t = lane; t < P; t += 64) lb[t] = (t < count) ? inj[lo + t] : 0xFFFFFFFFu;
        __syncthreads();
        for (int k = 2; k <= P; k <<= 1)
            for (int jj = k >> 1; jj > 0; jj >>= 1) {
                for (int e = lane; e < P; e += 64) {
                    int p = e ^ jj;
                    if (p > e) {
                        unsigned a = lb[e], b2 = lb[p];
                        bool up = ((e & k) == 0);
                        if ((a > b2) == up) { lb[e] = b2; lb[p] = a; }
                    }
                }
                __syncthreads();
            }
        for (int t = lane; t < count; t += 64) outj[lo + t] = lb[t];
    }
}

// ---------------- emd ----------------
__global__ __launch_bounds__(256) void k_emd(const unsigned* __restrict__ keys,
                                             float* __restrict__ emd) {
    __shared__ float red[4];
    int b = blockIdx.x;
    const unsigned* sp = keys + (size_t)b * SORTN_;
    const unsigned* st = keys + (size_t)(B_ + b) * SORTN_;
    float s = 0.f;
    for (int i = threadIdx.x; i < SORTN_; i += 256)
        s += fabsf(k2f(sp[i]) - k2f(st[i]));
    #pragma unroll
    for (int off = 32; off > 0; off >>= 1) s += __shfl_down(s, off);
    int w = threadIdx.x >> 6, lane = threadIdx.x & 63;
    if (lane == 0) red[w] = s;
    __syncthreads();
    if (threadIdx.x == 0) emd[b] = red[0] + red[1] + red[2] + red[3];
}

// ---------------- finalize ----------------
__device__ __forceinline__ float block_reduce256(float v, float* red) {
    #pragma unroll
    for (int off = 32; off > 0; off >>= 1) v += __shfl_down(v, off);
    int w = threadIdx.x >> 6, lane = threadIdx.x & 63;
    __syncthreads();
    if (lane == 0) red[w] = v;
    __syncthreads();
    return red[0] + red[1] + red[2] + red[3];
}

__global__ __launch_bounds__(256) void k_final(const unsigned* __restrict__ colmin,
                                               const float* __restrict__ maeP,
                                               const float* __restrict__ minbP,
                                               const float* __restrict__ emd,
                                               float* __restrict__ out) {
    __shared__ float red[4];
    int tid = threadIdx.x;
    float s1 = 0.f, s2 = 0.f, s3 = 0.f;
    for (int i = tid; i < B_ * N_; i += 256) s1 += __uint_as_float(colmin[i]);
    for (int i = tid; i < 8192; i += 256) s2 += maeP[i];
    for (int i = tid; i < 256; i += 256) s3 += minbP[i];
    float colmin_sum = block_reduce256(s1, red);
    float mae_sum    = block_reduce256(s2, red);
    float minb_sum   = block_reduce256(s3, red);
    if (tid < B_) {
        float mae  = mae_sum * (1.0f / 4194304.0f);
        float cham = colmin_sum * (1.0f / 32768.0f)
                   + minb_sum * (1.0f / 1048576.0f);
        out[tid] = mae + cham + emd[tid] * (1.0f / 131072.0f);
    }
}

extern "C" void kernel_launch(void* const* d_in, const int* in_sizes, int n_in,
                              void* d_out, int out_size, void* d_ws, size_t ws_size,
                              hipStream_t stream) {
    const float* pred = (const float*)d_in[0];
    const float* tgt  = (const float*)d_in[1];
    float* out = (float*)d_out;
    char* ws = (char*)d_ws;

    unsigned* colmin = (unsigned*)(ws + OFF_COLMIN);
    float* pnorm     = (float*)(ws + OFF_PNORM);
    float* tnorm     = (float*)(ws + OFF_TNORM);
    float* emd       = (float*)(ws + OFF_EMD);
    float* maeP      = (float*)(ws + OFF_MAEP);
    float* minbP     = (float*)(ws + OFF_MINBP);
    unsigned* minb   = (unsigned*)(ws + OFF_MINB);
    unsigned* spl    = (unsigned*)(ws + OFF_SPL);
    unsigned* base   = (unsigned*)(ws + OFF_BASE);
    unsigned* cnt    = (unsigned*)(ws + OFF_CNT);
    unsigned* keysA  = (unsigned*)(ws + OFF_KEYSA);
    unsigned* keysB  = (unsigned*)(ws + OFF_KEYSB);

    hipLaunchKernelGGL(k_init, dim3(512), dim3(256), 0, stream, colmin, minb);
    hipLaunchKernelGGL(k_prep, dim3(8192), dim3(256), 0, stream,
                       pred, tgt, pnorm, tnorm, keysA, maeP);
    hipLaunchKernelGGL(k_chamfer, dim3(16, 16, 4), dim3(256), 0, stream,
                       pred, tgt, pnorm, tnorm, colmin, minb);
    hipLaunchKernelGGL(k_redminb, dim3(256), dim3(256), 0, stream, minb, minbP);
    // minb region now dead -> spl/base/cnt alias it
    hipLaunchKernelGGL(k_splitters, dim3(JOBS_), dim3(256), 0, stream, keysA, spl);
    hipLaunchKernelGGL(k_zerobase, dim3(128), dim3(256), 0, stream, base);
    hipLaunchKernelGGL(k_hist, dim3(16, JOBS_), dim3(256), 0, stream, keysA, spl, base);
    hipLaunchKernelGGL(k_scan, dim3(JOBS_), dim3(256), 0, stream, base, cnt);
    hipLaunchKernelGGL(k_scatter, dim3(16, JOBS_), dim3(256), 0, stream,
                       keysA, spl, cnt, keysB);
    hipLaunchKernelGGL(k_bsort, dim3(JOBS_, JOBS_), dim3(64), 0, stream,
                       base, keysB, keysA);
    hipLaunchKernelGGL(k_emd, dim3(B_), dim3(256), 0, stream, keysA, emd);
    hipLaunchKernelGGL(k_final, dim3(1), dim3(256), 0, stream,
                       colmin, maeP, minbP, emd, out);
}

// Round 3
// 599.544 us; speedup vs baseline: 3.1254x; 3.1254x over previous
//
#include <hip/hip_runtime.h>
#include <stdint.h>

// CustomLoss: out[b] = MAE(all) + [mean(min_n d) + mean(min_b d)] + EMD1d(b)
// pred/target [32,1024,128] fp32 -> out 32 fp32.
//
// ws layout (total 72,351,744 B, same as proven rounds):
//   colmin  u32[32768]     @ 0
//   pnorm   f32[32768]     @ 131072
//   tnorm   f32[32768]     @ 262144
//   emdP    f32[512]       @ 393216   (16 partials x 32 batches)
//   maeP    f32[8192]      @ 395264
//   minbP   f32[256]       @ 428032
//   minb    u32[1M]        @ 1048576  (4MB; ALSO hosts radix hist g_h before k_init)
//   keysA   u32[64*131072] @ 5242880
//   keysB   u32[64*131072] @ 38797312

#define B_ 32
#define N_ 1024
#define D_ 128
#define SORTN_ (N_ * D_)
#define JOBS_ 64

#define OFF_COLMIN 0
#define OFF_PNORM  131072
#define OFF_TNORM  262144
#define OFF_EMDP   393216
#define OFF_MAEP   395264
#define OFF_MINBP  428032
#define OFF_MINB   1048576
#define OFF_HIST   1048576
#define OFF_KEYSA  5242880
#define OFF_KEYSB  38797312

__device__ __forceinline__ unsigned f2k(float f) {
    unsigned u = __float_as_uint(f);
    return (u & 0x80000000u) ? ~u : (u | 0x80000000u);
}
__device__ __forceinline__ float k2f(unsigned k) {
    unsigned u = (k & 0x80000000u) ? (k & 0x7FFFFFFFu) : ~k;
    return __uint_as_float(u);
}

// ---------------- init: +inf the min buffers (AFTER radix frees hist) ----------------
__global__ __launch_bounds__(256) void k_init(unsigned* colmin, unsigned* minb) {
    int i = blockIdx.x * 256 + threadIdx.x;
    int stride = gridDim.x * 256;
    for (int j = i; j < B_ * N_; j += stride) colmin[j] = 0x7F800000u;
    for (int j = i; j < N_ * N_; j += stride) minb[j] = 0x7F800000u;
}

// ---------------- prep: MAE partials, row norms, sort keys ----------------
__global__ __launch_bounds__(256) void k_prep(const float* __restrict__ pred,
                                              const float* __restrict__ tgt,
                                              float* __restrict__ pnorm,
                                              float* __restrict__ tnorm,
                                              unsigned* __restrict__ keys,
                                              float* __restrict__ maeP) {
    __shared__ float red[4];
    int w = threadIdx.x >> 6, lane = threadIdx.x & 63;
    int row = blockIdx.x * 4 + w;
    const float2* p2 = (const float2*)(pred + (size_t)row * D_);
    const float2* t2 = (const float2*)(tgt + (size_t)row * D_);
    float2 p = p2[lane];
    float2 t = t2[lane];
    float mae = fabsf(p.x - t.x) + fabsf(p.y - t.y);
    float pn = p.x * p.x + p.y * p.y;
    float tn = t.x * t.x + t.y * t.y;
    int b = row >> 10, r1 = row & 1023;
    unsigned* kp = keys + (size_t)b * SORTN_ + r1 * D_ + lane * 2;
    kp[0] = f2k(p.x); kp[1] = f2k(p.y);
    unsigned* kt = keys + (size_t)(B_ + b) * SORTN_ + r1 * D_ + lane * 2;
    kt[0] = f2k(t.x); kt[1] = f2k(t.y);
    #pragma unroll
    for (int off = 32; off > 0; off >>= 1) {
        mae += __shfl_down(mae, off);
        pn  += __shfl_down(pn, off);
        tn  += __shfl_down(tn, off);
    }
    if (lane == 0) { pnorm[row] = pn; tnorm[row] = tn; red[w] = mae; }
    __syncthreads();
    if (threadIdx.x == 0) maeP[blockIdx.x] = red[0] + red[1] + red[2] + red[3];
}

// ---------------- chamfer: 4x4 register tile, K chunked 32-wide ----------------
// grid (16 m,16 n,4 bg), block 256 = 16x16. LDS 22.5KB -> 7 blocks/CU.
#define LDP 36
__global__ __launch_bounds__(256) void k_chamfer(const float* __restrict__ pred,
                                                 const float* __restrict__ tgt,
                                                 const float* __restrict__ pnorm,
                                                 const float* __restrict__ tnorm,
                                                 unsigned* __restrict__ colmin,
                                                 unsigned* __restrict__ minb) {
    __shared__ float Xs[64][LDP];
    __shared__ float Ys[64][LDP];
    __shared__ float colred[1024];
    int m0 = blockIdx.x * 64, n0 = blockIdx.y * 64, bg = blockIdx.z;
    int tid = threadIdx.x, ty = tid >> 4, tx = tid & 15;

    float mreg[4][4];
    #pragma unroll
    for (int i = 0; i < 4; i++)
        #pragma unroll
        for (int j = 0; j < 4; j++) mreg[i][j] = 3.0e38f;

    for (int bi = 0; bi < 8; ++bi) {
        int b = bg * 8 + bi;
        float acc[4][4];
        #pragma unroll
        for (int i = 0; i < 4; i++)
            #pragma unroll
            for (int j = 0; j < 4; j++) acc[i][j] = 0.f;

        for (int kc0 = 0; kc0 < 128; kc0 += 32) {
            __syncthreads();
            #pragma unroll
            for (int q = 0; q < 2; q++) {
                int l2 = q * 256 + tid;
                int row = l2 >> 3, kq = l2 & 7;
                *(float4*)&Xs[row][kq * 4] =
                    *(const float4*)&pred[((size_t)b * N_ + n0 + row) * D_ + kc0 + kq * 4];
                *(float4*)&Ys[row][kq * 4] =
                    *(const float4*)&tgt[((size_t)b * N_ + m0 + row) * D_ + kc0 + kq * 4];
            }
            __syncthreads();
            #pragma unroll
            for (int kc = 0; kc < 8; ++kc) {
                float4 xf[4], yf[4];
                #pragma unroll
                for (int i = 0; i < 4; i++) xf[i] = *(float4*)&Xs[ty + 16 * i][kc * 4];
                #pragma unroll
                for (int j = 0; j < 4; j++) yf[j] = *(float4*)&Ys[tx + 16 * j][kc * 4];
                #pragma unroll
                for (int i = 0; i < 4; i++)
                    #pragma unroll
                    for (int j = 0; j < 4; j++) {
                        acc[i][j] += xf[i].x * yf[j].x + xf[i].y * yf[j].y
                                   + xf[i].z * yf[j].z + xf[i].w * yf[j].w;
                    }
            }
        }

        float pn_[4], tn_[4];
        #pragma unroll
        for (int i = 0; i < 4; i++) pn_[i] = pnorm[(size_t)b * N_ + n0 + ty + 16 * i];
        #pragma unroll
        for (int j = 0; j < 4; j++) tn_[j] = tnorm[(size_t)b * N_ + m0 + tx + 16 * j];

        float cmin[4] = {3.0e38f, 3.0e38f, 3.0e38f, 3.0e38f};
        #pragma unroll
        for (int i = 0; i < 4; i++)
            #pragma unroll
            for (int j = 0; j < 4; j++) {
                float sq = pn_[i] + tn_[j] - 2.0f * acc[i][j];
                float d = sqrtf(fmaxf(sq, 1e-12f));
                mreg[i][j] = fminf(mreg[i][j], d);
                cmin[j] = fminf(cmin[j], d);
            }
        #pragma unroll
        for (int j = 0; j < 4; j++) colred[ty * 64 + tx + 16 * j] = cmin[j];
        __syncthreads();
        if (tid < 64) {
            float v = 3.0e38f;
            #pragma unroll
            for (int q = 0; q < 16; q++) v = fminf(v, colred[q * 64 + tid]);
            atomicMin(&colmin[(size_t)b * N_ + m0 + tid], __float_as_uint(v));
        }
    }
    #pragma unroll
    for (int i = 0; i < 4; i++)
        #pragma unroll
        for (int j = 0; j < 4; j++)
            atomicMin(&minb[(size_t)(n0 + ty + 16 * i) * N_ + m0 + tx + 16 * j],
                      __float_as_uint(mreg[i][j]));
}

// ---------------- reduce minb -> per-block partials ----------------
__global__ __launch_bounds__(256) void k_redminb(const unsigned* __restrict__ minb,
                                                 float* __restrict__ minbP) {
    __shared__ float red[4];
    float s = 0.f;
    for (int i = blockIdx.x * 256 + threadIdx.x; i < N_ * N_; i += 256 * 256)
        s += __uint_as_float(minb[i]);
    #pragma unroll
    for (int off = 32; off > 0; off >>= 1) s += __shfl_down(s, off);
    int w = threadIdx.x >> 6, lane = threadIdx.x & 63;
    if (lane == 0) red[w] = s;
    __syncthreads();
    if (threadIdx.x == 0) minbP[blockIdx.x] = red[0] + red[1] + red[2] + red[3];
}

// ======== radix sort: 8-bit x 4 passes, hist/scan/scatter ========
// hist layout: g_h[job][digit*64 + tile*4 + wave], 64*16384 u32 = 4MB.

__global__ __launch_bounds__(256) void k_rhist(const unsigned* __restrict__ src,
                                               unsigned* __restrict__ g_h, int shift) {
    __shared__ unsigned wh[4][256];
    int t = blockIdx.x, j = blockIdx.y, tid = threadIdx.x;
    int w = tid >> 6, lane = tid & 63;
    #pragma unroll
    for (int q = 0; q < 4; q++) wh[q][tid] = 0u;
    __syncthreads();
    const unsigned* seg = src + (size_t)j * SORTN_ + t * 8192 + w * 2048;
    #pragma unroll 4
    for (int i = 0; i < 32; i++) {
        unsigned d = (seg[i * 64 + lane] >> shift) & 255u;
        atomicAdd(&wh[w][d], 1u);
    }
    __syncthreads();
    #pragma unroll
    for (int q = 0; q < 4; q++)
        g_h[(size_t)j * 16384 + tid * 64 + t * 4 + q] = wh[q][tid];
}

__global__ __launch_bounds__(256) void k_rscan(unsigned* __restrict__ g_h) {
    __shared__ unsigned partial[256];
    int j = blockIdx.x, tid = threadIdx.x;
    unsigned* hj = g_h + (size_t)j * 16384;
    unsigned s = 0;
    #pragma unroll 8
    for (int q = 0; q < 64; q++) s += hj[tid * 64 + q];
    partial[tid] = s;
    __syncthreads();
    for (int off = 1; off < 256; off <<= 1) {
        unsigned add = (tid >= off) ? partial[tid - off] : 0u;
        __syncthreads();
        partial[tid] += add;
        __syncthreads();
    }
    unsigned run = partial[tid] - s;   // exclusive base for digit=tid
    #pragma unroll 8
    for (int q = 0; q < 64; q++) {
        unsigned c = hj[tid * 64 + q];
        hj[tid * 64 + q] = run;
        run += c;
    }
}

// stable scatter: ballot-rank within wave (deterministic), block-local LDS reorder,
// coalesced bin-run copy-out. LDS ~51KB -> 3 blocks/CU.
__global__ __launch_bounds__(256) void k_rscatter(const unsigned* __restrict__ src,
                                                  const unsigned* __restrict__ gbase,
                                                  unsigned* __restrict__ dst, int shift) {
    __shared__ unsigned wrun[4][256];
    __shared__ unsigned waveoff[4][256];
    __shared__ unsigned Lbase[256];
    __shared__ unsigned partial[256];
    __shared__ int shiftb[256];
    __shared__ unsigned sorted[8192];
    __shared__ unsigned char binb[8192];
    int t = blockIdx.x, j = blockIdx.y, tid = threadIdx.x;
    int w = tid >> 6, lane = tid & 63;
    #pragma unroll
    for (int q = 0; q < 4; q++) wrun[q][tid] = 0u;
    __syncthreads();

    const unsigned* seg = src + (size_t)j * SORTN_ + t * 8192 + w * 2048;
    unsigned k[32];
    unsigned rk[32];
    unsigned long long ltm = (1ull << lane) - 1ull;
    #pragma unroll
    for (int i = 0; i < 32; i++) {
        unsigned key = seg[i * 64 + lane];
        k[i] = key;
        unsigned d = (key >> shift) & 255u;
        unsigned long long m = ~0ull;
        #pragma unroll
        for (int bit = 0; bit < 8; bit++) {
            unsigned long long bm = __ballot((d >> bit) & 1u);
            m &= ((d >> bit) & 1u) ? bm : ~bm;
        }
        int rnk = __popcll(m & ltm);
        int leader = __ffsll((unsigned long long)m) - 1;
        int cnt = __popcll(m);
        unsigned base = 0;
        if (lane == leader) base = atomicAdd(&wrun[w][d], (unsigned)cnt);
        base = __shfl(base, leader);
        rk[i] = base + (unsigned)rnk;
    }
    __syncthreads();

    unsigned c0 = wrun[0][tid], c1 = wrun[1][tid], c2 = wrun[2][tid], c3 = wrun[3][tid];
    waveoff[0][tid] = 0u; waveoff[1][tid] = c0;
    waveoff[2][tid] = c0 + c1; waveoff[3][tid] = c0 + c1 + c2;
    unsigned btot = c0 + c1 + c2 + c3;
    partial[tid] = btot;
    __syncthreads();
    for (int off = 1; off < 256; off <<= 1) {
        unsigned add = (tid >= off) ? partial[tid - off] : 0u;
        __syncthreads();
        partial[tid] += add;
        __syncthreads();
    }
    unsigned lb = partial[tid] - btot;
    Lbase[tid] = lb;
    shiftb[tid] = (int)gbase[(size_t)j * 16384 + tid * 64 + t * 4] - (int)lb;
    __syncthreads();

    #pragma unroll
    for (int i = 0; i < 32; i++) {
        unsigned d = (k[i] >> shift) & 255u;
        unsigned lp = Lbase[d] + waveoff[w][d] + rk[i];
        sorted[lp] = k[i];
        binb[lp] = (unsigned char)d;
    }
    __syncthreads();

    unsigned* dstj = dst + (size_t)j * SORTN_;
    #pragma unroll 4
    for (int it = 0; it < 32; it++) {
        int q = it * 256 + tid;
        unsigned d = binb[q];
        dstj[shiftb[d] + q] = sorted[q];
    }
}

// ---------------- emd partials ----------------
__global__ __launch_bounds__(256) void k_emdp(const unsigned* __restrict__ keys,
                                              float* __restrict__ emdP) {
    __shared__ float red[4];
    int c = blockIdx.x, b = blockIdx.y;
    const unsigned* sp = keys + (size_t)b * SORTN_ + c * 8192;
    const unsigned* st = keys + (size_t)(B_ + b) * SORTN_ + c * 8192;
    float s = 0.f;
    for (int i = threadIdx.x; i < 8192; i += 256)
        s += fabsf(k2f(sp[i]) - k2f(st[i]));
    #pragma unroll
    for (int off = 32; off > 0; off >>= 1) s += __shfl_down(s, off);
    int w = threadIdx.x >> 6, lane = threadIdx.x & 63;
    if (lane == 0) red[w] = s;
    __syncthreads();
    if (threadIdx.x == 0) emdP[b * 16 + c] = red[0] + red[1] + red[2] + red[3];
}

// ---------------- finalize ----------------
__device__ __forceinline__ float block_reduce256(float v, float* red) {
    #pragma unroll
    for (int off = 32; off > 0; off >>= 1) v += __shfl_down(v, off);
    int w = threadIdx.x >> 6, lane = threadIdx.x & 63;
    __syncthreads();
    if (lane == 0) red[w] = v;
    __syncthreads();
    return red[0] + red[1] + red[2] + red[3];
}

__global__ __launch_bounds__(256) void k_final(const unsigned* __restrict__ colmin,
                                               const float* __restrict__ maeP,
                                               const float* __restrict__ minbP,
                                               const float* __restrict__ emdP,
                                               float* __restrict__ out) {
    __shared__ float red[4];
    int tid = threadIdx.x;
    float s1 = 0.f, s2 = 0.f, s3 = 0.f;
    for (int i = tid; i < B_ * N_; i += 256) s1 += __uint_as_float(colmin[i]);
    for (int i = tid; i < 8192; i += 256) s2 += maeP[i];
    for (int i = tid; i < 256; i += 256) s3 += minbP[i];
    float colmin_sum = block_reduce256(s1, red);
    float mae_sum    = block_reduce256(s2, red);
    float minb_sum   = block_reduce256(s3, red);
    if (tid < B_) {
        float e = 0.f;
        #pragma unroll
        for (int c = 0; c < 16; c++) e += emdP[tid * 16 + c];
        float mae  = mae_sum * (1.0f / 4194304.0f);
        float cham = colmin_sum * (1.0f / 32768.0f)
                   + minb_sum * (1.0f / 1048576.0f);
        out[tid] = mae + cham + e * (1.0f / 131072.0f);
    }
}

extern "C" void kernel_launch(void* const* d_in, const int* in_sizes, int n_in,
                              void* d_out, int out_size, void* d_ws, size_t ws_size,
                              hipStream_t stream) {
    const float* pred = (const float*)d_in[0];
    const float* tgt  = (const float*)d_in[1];
    float* out = (float*)d_out;
    char* ws = (char*)d_ws;

    unsigned* colmin = (unsigned*)(ws + OFF_COLMIN);
    float* pnorm     = (float*)(ws + OFF_PNORM);
    float* tnorm     = (float*)(ws + OFF_TNORM);
    float* emdP      = (float*)(ws + OFF_EMDP);
    float* maeP      = (float*)(ws + OFF_MAEP);
    float* minbP     = (float*)(ws + OFF_MINBP);
    unsigned* minb   = (unsigned*)(ws + OFF_MINB);
    unsigned* g_h    = (unsigned*)(ws + OFF_HIST);   // aliases minb (radix first)
    unsigned* keysA  = (unsigned*)(ws + OFF_KEYSA);
    unsigned* keysB  = (unsigned*)(ws + OFF_KEYSB);

    hipLaunchKernelGGL(k_prep, dim3(8192), dim3(256), 0, stream,
                       pred, tgt, pnorm, tnorm, keysA, maeP);

    // 4 LSD radix passes (keysA -> B -> A -> B -> A)
    unsigned* bufs[2] = {keysA, keysB};
    for (int pass = 0; pass < 4; ++pass) {
        unsigned* s = bufs[pass & 1];
        unsigned* d = bufs[(pass & 1) ^ 1];
        int shift = pass * 8;
        hipLaunchKernelGGL(k_rhist, dim3(16, JOBS_), dim3(256), 0, stream, s, g_h, shift);
        hipLaunchKernelGGL(k_rscan, dim3(JOBS_), dim3(256), 0, stream, g_h);
        hipLaunchKernelGGL(k_rscatter, dim3(16, JOBS_), dim3(256), 0, stream,
                           s, g_h, d, shift);
    }
    hipLaunchKernelGGL(k_emdp, dim3(16, B_), dim3(256), 0, stream, keysA, emdP);

    // hist region now dead -> minb/colmin init, then chamfer
    hipLaunchKernelGGL(k_init, dim3(512), dim3(256), 0, stream, colmin, minb);
    hipLaunchKernelGGL(k_chamfer, dim3(16, 16, 4), dim3(256), 0, stream,
                       pred, tgt, pnorm, tnorm, colmin, minb);
    hipLaunchKernelGGL(k_redminb, dim3(256), dim3(256), 0, stream, minb, minbP);
    hipLaunchKernelGGL(k_final, dim3(1), dim3(256), 0, stream,
                       colmin, maeP, minbP, emdP, out);
}